// Round 4
// baseline (589.751 us; speedup 1.0000x reference)
//
#include <hip/hip_runtime.h>
#include <hip/hip_bf16.h>

namespace {
constexpr int Md = 4096, Kd = 4096, Nd = 12288;
constexpr int BM = 256, BN = 128, BK = 64;
constexpr int TK = Kd / BK;                        // 64
constexpr int THREADS = 512;
constexpr size_t A_BYTES = (size_t)Md * Kd * 2;    // bf16 copy of X in d_ws
constexpr int AS_T = BM * BK;                      // shorts per A tile (16384)
constexpr int BS_T = BN * BK;                      // shorts per B tile (8192)
constexpr int LDS_BYTES = (2 * AS_T + 2 * BS_T) * 2;  // 98304

typedef __attribute__((ext_vector_type(4))) float f4;
typedef __attribute__((ext_vector_type(8))) short b8;

__device__ __forceinline__ unsigned cvtpk(float lo, float hi) {
  unsigned r;
  asm("v_cvt_pk_bf16_f32 %0, %1, %2" : "=v"(r) : "v"(lo), "v"(hi));
  return r;
}

__global__ __launch_bounds__(256)
void cvtA_kernel(const float* __restrict__ X, unsigned short* __restrict__ Xb, int n8) {
  int i = blockIdx.x * blockDim.x + threadIdx.x;
  const int stride = gridDim.x * blockDim.x;
  for (; i < n8; i += stride) {
    const f4* p = (const f4*)X + (size_t)i * 2;
    f4 a = p[0], b = p[1];
    uint4 o;
    o.x = cvtpk(a[0], a[1]); o.y = cvtpk(a[2], a[3]);
    o.z = cvtpk(b[0], b[1]); o.w = cvtpk(b[2], b[3]);
    ((uint4*)Xb)[i] = o;
  }
}

template<bool AWS>
__global__ __launch_bounds__(THREADS, 2)
void qgemm3(const float* __restrict__ X, const unsigned short* __restrict__ Xb,
            const int* __restrict__ QW, const int* __restrict__ QZ,
            const float* __restrict__ SC, const float* __restrict__ BS,
            float* __restrict__ OUT)
{
  extern __shared__ char smem[];
  unsigned short* As = (unsigned short*)smem;                      // [2][AS_T]
  unsigned short* Bs = (unsigned short*)(smem + 2 * AS_T * 2);     // [2][BS_T]

  const int nwg = gridDim.x;
  const int cpx = nwg >> 3;
  const int b = blockIdx.x;
  const int swz = (b & 7) * cpx + (b >> 3);       // grid 1536 % 8 == 0 -> bijective
  const int bm = swz / (Nd / BN), bn = swz % (Nd / BN);
  const int m0 = bm * BM, n0 = bn * BN;

  const int tid = threadIdx.x, lane = tid & 63;
  const int wid = tid >> 6;
  const int wr = wid >> 1, wc = wid & 1;          // 4x2 waves, each 64x64 output

  const int n_l = tid & 127;                      // B staging: n within tile
  const int k8b = (tid >> 7) * 2;                 // B staging: first of 2 k8-rows

  f4 acc[4][4];
  #pragma unroll
  for (int i = 0; i < 4; ++i)
    #pragma unroll
    for (int j = 0; j < 4; ++j) acc[i][j] = {0.0f, 0.0f, 0.0f, 0.0f};

  // --- A staging: LDS linear dest, pre-swizzled global source (kb ^ (r&7)) ---
  auto stageA = [&](int t, int buf) {
    #pragma unroll
    for (int i = 0; i < 4; ++i) {
      const int c = i * THREADS + tid;            // 16B chunk index, 0..2047
      const int r = c >> 3, kbl = c & 7;
      const unsigned short* src = Xb + (size_t)(m0 + r) * Kd + t * BK + ((kbl ^ (r & 7)) << 3);
      __builtin_amdgcn_global_load_lds(
          (const __attribute__((address_space(1))) unsigned*)src,
          (__attribute__((address_space(3))) unsigned*)(As + buf * AS_T + c * 8),
          16, 0, 0);
    }
  };
  auto stageA_f = [&](int t, int buf) {           // fallback: fp32 load + cvt inline
    #pragma unroll
    for (int i = 0; i < 4; ++i) {
      const int c = i * THREADS + tid;
      const int r = c >> 3, kbl = c & 7;
      const f4* src = (const f4*)(X + (size_t)(m0 + r) * Kd + t * BK + ((kbl ^ (r & 7)) << 3));
      f4 a = src[0], bb = src[1];
      uint4 o;
      o.x = cvtpk(a[0], a[1]); o.y = cvtpk(a[2], a[3]);
      o.z = cvtpk(bb[0], bb[1]); o.w = cvtpk(bb[2], bb[3]);
      *(uint4*)(As + buf * AS_T + c * 8) = o;
    }
  };

  // --- B: packed-word loads (2/tile), shared scale/zero per group pair ---
  auto loadQW = [&](int t, int* w) {
    const int* qp = QW + (size_t)(t * 8 + k8b) * Nd + n0 + n_l;
    w[0] = qp[0];
    w[1] = qp[Nd];
  };
  auto loadSZ = [&](int g, float& s, float& negc) {
    s = SC[(size_t)g * Nd + n0 + n_l];
    const int nab = n0 + n_l;
    const int z32 = QZ[(size_t)g * (Nd / 8) + (nab >> 3)];
    const int z = (z32 >> ((nab & 7) * 4)) & 15;
    negc = -(float)(z + 1) * s;                   // w = fma(q, s, negc)
  };
  auto writeB = [&](const int* w, float s, float negc, int buf) {
    #pragma unroll
    for (int i = 0; i < 2; ++i) {
      const unsigned q = (unsigned)w[i];
      const int k8 = k8b + i;
      float f[8];
      #pragma unroll
      for (int j = 0; j < 8; ++j)
        f[j] = __builtin_fmaf((float)((q >> (4 * j)) & 15u), s, negc);
      uint4 o;
      o.x = cvtpk(f[0], f[1]); o.y = cvtpk(f[2], f[3]);
      o.z = cvtpk(f[4], f[5]); o.w = cvtpk(f[6], f[7]);
      const int chunk = (k8 ^ (n_l & 7)) << 3;    // 8 shorts per 16B chunk
      *(uint4*)(Bs + buf * BS_T + n_l * BK + chunk) = o;
    }
  };

  auto mfma_tile = [&](int cb) {
    const unsigned short* Ab = As + cb * AS_T;
    const unsigned short* Bb = Bs + cb * BS_T;
    #pragma unroll
    for (int ks = 0; ks < 2; ++ks) {
      b8 af[4], bf[4];
      const int kb = ks * 4 + (lane >> 4);
      #pragma unroll
      for (int mi = 0; mi < 4; ++mi) {
        const int r = wr * 64 + mi * 16 + (lane & 15);
        af[mi] = *(const b8*)&Ab[r * BK + ((kb ^ (r & 7)) << 3)];
      }
      #pragma unroll
      for (int ni = 0; ni < 4; ++ni) {
        const int cc = wc * 64 + ni * 16 + (lane & 15);
        bf[ni] = *(const b8*)&Bb[cc * BK + ((kb ^ (cc & 7)) << 3)];
      }
      #pragma unroll
      for (int mi = 0; mi < 4; ++mi)
        #pragma unroll
        for (int ni = 0; ni < 4; ++ni)
          acc[mi][ni] = __builtin_amdgcn_mfma_f32_16x16x32_bf16(af[mi], bf[ni], acc[mi][ni], 0, 0, 0);
    }
  };

  // B register pipeline: wE holds an even tile's packed words, wO an odd tile's.
  int wE[2], wO[2];
  float sCur, ncCur, sNxt, ncNxt;

  // prologue: tile 0 staged to buf0; tile 1's packed words prefetched
  if constexpr (AWS) stageA(0, 0); else stageA_f(0, 0);
  loadQW(0, wE);
  loadSZ(0, sCur, ncCur);                  // g=0 serves tiles 0 and 1
  writeB(wE, sCur, ncCur, 0);
  loadQW(1, wO);
  __syncthreads();                         // A0 DMA + B0 writes visible

  for (int t = 0; t < TK; t += 2) {
    // ---- even step: compute tile t from buf0; stage tile t+1 into buf1 ----
    if constexpr (AWS) stageA(t + 1, 1); else stageA_f(t + 1, 1);
    writeB(wO, sCur, ncCur, 1);            // tile t+1 (g = t/2)
    if (t + 2 < TK) {
      loadQW(t + 2, wE);
      loadSZ(t / 2 + 1, sNxt, ncNxt);      // g for tiles t+2, t+3
    }
    mfma_tile(0);
    __syncthreads();

    // ---- odd step: compute tile t+1 from buf1; stage tile t+2 into buf0 ----
    if (t + 2 < TK) {
      if constexpr (AWS) stageA(t + 2, 0); else stageA_f(t + 2, 0);
      writeB(wE, sNxt, ncNxt, 0);          // tile t+2 (g = t/2+1)
    }
    if (t + 3 < TK) loadQW(t + 3, wO);
    mfma_tile(1);
    __syncthreads();

    sCur = sNxt; ncCur = ncNxt;            // rotate group scale for next pair
  }

  // epilogue: C/D layout col = lane&15, row = (lane>>4)*4 + j
  #pragma unroll
  for (int ni = 0; ni < 4; ++ni) {
    const int gn = n0 + wc * 64 + ni * 16 + (lane & 15);
    const float bv = BS[gn];
    #pragma unroll
    for (int mi = 0; mi < 4; ++mi) {
      const int gm = m0 + wr * 64 + mi * 16 + ((lane >> 4) << 2);
      #pragma unroll
      for (int j = 0; j < 4; ++j)
        OUT[(size_t)(gm + j) * Nd + gn] = acc[mi][ni][j] + bv;
    }
  }
}
} // namespace

extern "C" void kernel_launch(void* const* d_in, const int* in_sizes, int n_in,
                              void* d_out, int out_size, void* d_ws, size_t ws_size,
                              hipStream_t stream) {
  const float* x  = (const float*)d_in[0];
  const int*   qw = (const int*)d_in[1];
  const int*   qz = (const int*)d_in[2];
  const float* sc = (const float*)d_in[3];
  const float* bs = (const float*)d_in[4];
  float* out = (float*)d_out;

  (void)hipFuncSetAttribute((const void*)qgemm3<true>,
                            hipFuncAttributeMaxDynamicSharedMemorySize, LDS_BYTES);
  (void)hipFuncSetAttribute((const void*)qgemm3<false>,
                            hipFuncAttributeMaxDynamicSharedMemorySize, LDS_BYTES);

  dim3 grid((Md / BM) * (Nd / BN));   // 16 * 96 = 1536
  if (ws_size >= A_BYTES) {
    unsigned short* xb = (unsigned short*)d_ws;
    const int n8 = Md * Kd / 8;
    cvtA_kernel<<<2048, 256, 0, stream>>>(x, xb, n8);
    qgemm3<true><<<grid, dim3(THREADS), LDS_BYTES, stream>>>(x, xb, qw, qz, sc, bs, out);
  } else {
    qgemm3<false><<<grid, dim3(THREADS), LDS_BYTES, stream>>>(x, nullptr, qw, qz, sc, bs, out);
  }
}

// Round 5
// 504.254 us; speedup vs baseline: 1.1696x; 1.1696x over previous
//
#include <hip/hip_runtime.h>
#include <hip/hip_bf16.h>

namespace {
constexpr int Md = 4096, Kd = 4096, Nd = 12288;
constexpr int BM = 256, BN = 128, BK = 64;
constexpr int TK = Kd / BK;                        // 64
constexpr int THREADS = 512;
constexpr size_t A_BYTES = (size_t)Md * Kd * 2;    // bf16 copy of X in d_ws
constexpr int AS_T = BM * BK;                      // shorts per A tile (16384)
constexpr int BS_T = BN * BK;                      // shorts per B tile (8192)
constexpr int LDS_BYTES = (2 * AS_T + 2 * BS_T) * 2;   // 98304 (1 block/CU)
constexpr int LDS_FB    = (2 * AS_T + BS_T) * 2;       // 81920 (fallback)

typedef __attribute__((ext_vector_type(4))) float f4;
typedef __attribute__((ext_vector_type(8))) short b8;

#define WAIT_LGKM0 asm volatile("s_waitcnt lgkmcnt(0)" ::: "memory")
#define WAIT_VM(n) asm volatile("s_waitcnt vmcnt(" #n ")" ::: "memory")

__device__ __forceinline__ unsigned cvtpk(float lo, float hi) {
  unsigned r;
  asm("v_cvt_pk_bf16_f32 %0, %1, %2" : "=v"(r) : "v"(lo), "v"(hi));
  return r;
}

__global__ __launch_bounds__(256)
void cvtA_kernel(const float* __restrict__ X, unsigned short* __restrict__ Xb, int n8) {
  int i = blockIdx.x * blockDim.x + threadIdx.x;
  const int stride = gridDim.x * blockDim.x;
  for (; i < n8; i += stride) {
    const f4* p = (const f4*)X + (size_t)i * 2;
    f4 a = p[0], b = p[1];
    uint4 o;
    o.x = cvtpk(a[0], a[1]); o.y = cvtpk(a[2], a[3]);
    o.z = cvtpk(b[0], b[1]); o.w = cvtpk(b[2], b[3]);
    ((uint4*)Xb)[i] = o;
  }
}

// ---------------- main kernel: dbuf A+B, counted-vmcnt schedule ----------------
__global__ __launch_bounds__(THREADS, 2)
void qgemm4(const unsigned short* __restrict__ Xb,
            const int* __restrict__ QW, const int* __restrict__ QZ,
            const float* __restrict__ SC, const float* __restrict__ BS,
            float* __restrict__ OUT)
{
  extern __shared__ char smem[];
  unsigned short* As = (unsigned short*)smem;                      // [2][AS_T]
  unsigned short* Bs = (unsigned short*)(smem + 2 * AS_T * 2);     // [2][BS_T]

  const int nwg = gridDim.x, cpx = nwg >> 3, b = blockIdx.x;
  const int swz = (b & 7) * cpx + (b >> 3);       // 1536 % 8 == 0 -> bijective
  const int bm = swz / (Nd / BN), bn = swz % (Nd / BN);
  const int m0 = bm * BM, n0 = bn * BN;

  const int tid = threadIdx.x, lane = tid & 63, wid = tid >> 6;
  const int wr = wid >> 1, wc = wid & 1;          // 4x2 waves, each 64x64
  const int n_l = tid & 127;
  const int k8b = (tid >> 7) * 2;
  const int nab = n0 + n_l;

  f4 acc[4][4];
  #pragma unroll
  for (int i = 0; i < 4; ++i)
    #pragma unroll
    for (int j = 0; j < 4; ++j) acc[i][j] = {0.0f, 0.0f, 0.0f, 0.0f};

  // A staging: linear LDS dest, pre-swizzled global source (4 x global_load_lds 16B)
  auto stageA = [&](int t, int buf) {
    #pragma unroll
    for (int i = 0; i < 4; ++i) {
      const int c = i * THREADS + tid;
      const int r = c >> 3, kbl = c & 7;
      const unsigned short* src = Xb + (size_t)(m0 + r) * Kd + t * BK + ((kbl ^ (r & 7)) << 3);
      __builtin_amdgcn_global_load_lds(
          (const __attribute__((address_space(1))) unsigned*)src,
          (__attribute__((address_space(3))) unsigned*)(As + buf * AS_T + c * 8),
          16, 0, 0);
    }
  };
  auto loadQWf = [&](int t, int& w0, int& w1) {
    const int* qp = QW + (size_t)(t * 8 + k8b) * Nd + nab;
    w0 = qp[0]; w1 = qp[Nd];
  };
  auto loadSZf = [&](int g, float& s, int& z32) {
    s = SC[(size_t)g * Nd + nab];
    z32 = QZ[(size_t)g * (Nd / 8) + (nab >> 3)];
  };
  auto writeB = [&](int w0, int w1, float s, int z32, int buf) {
    const int z = (z32 >> ((nab & 7) * 4)) & 15;
    const float negc = -(float)(z + 1) * s;
    const int w[2] = {w0, w1};
    #pragma unroll
    for (int i = 0; i < 2; ++i) {
      const unsigned q = (unsigned)w[i];
      const int k8 = k8b + i;
      float f[8];
      #pragma unroll
      for (int j = 0; j < 8; ++j)
        f[j] = __builtin_fmaf((float)((q >> (4 * j)) & 15u), s, negc);
      uint4 o;
      o.x = cvtpk(f[0], f[1]); o.y = cvtpk(f[2], f[3]);
      o.z = cvtpk(f[4], f[5]); o.w = cvtpk(f[6], f[7]);
      *(uint4*)(Bs + buf * BS_T + n_l * BK + ((k8 ^ (n_l & 7)) << 3)) = o;
    }
  };
  auto mfma_tile = [&](int cb) {
    const unsigned short* Ab = As + cb * AS_T;
    const unsigned short* Bb = Bs + cb * BS_T;
    #pragma unroll
    for (int ks = 0; ks < 2; ++ks) {
      b8 af[4], bf[4];
      const int kb = ks * 4 + (lane >> 4);
      #pragma unroll
      for (int mi = 0; mi < 4; ++mi) {
        const int r = wr * 64 + mi * 16 + (lane & 15);
        af[mi] = *(const b8*)&Ab[r * BK + ((kb ^ (r & 7)) << 3)];
      }
      #pragma unroll
      for (int ni = 0; ni < 4; ++ni) {
        const int cc = wc * 64 + ni * 16 + (lane & 15);
        bf[ni] = *(const b8*)&Bb[cc * BK + ((kb ^ (cc & 7)) << 3)];
      }
      #pragma unroll
      for (int mi = 0; mi < 4; ++mi)
        #pragma unroll
        for (int ni = 0; ni < 4; ++ni)
          acc[mi][ni] = __builtin_amdgcn_mfma_f32_16x16x32_bf16(af[mi], bf[ni], acc[mi][ni], 0, 0, 0);
    }
  };

  // regs: wE = even-tile packed words, wO = odd-tile; (sC,zC) current group pair
  int wE0, wE1, wO0, wO1, zC, zN;
  float sC, sN;

  // ---- prologue: establish invariant (enter step 0 with only QW(1) in flight)
  loadQWf(0, wE0, wE1);        // +2
  loadSZf(0, sC, zC);          // +2
  stageA(0, 0);                // +4
  writeB(wE0, wE1, sC, zC, 0); // consumes QW(0)/SZ(0)
  loadQWf(1, wO0, wO1);        // +2  -> outstanding: A(0)x4 + QW(1)x2
  __builtin_amdgcn_sched_barrier(0);
  WAIT_LGKM0;
  WAIT_VM(2);                  // A(0) done; QW(1) stays in flight
  __builtin_amdgcn_s_barrier();
  __builtin_amdgcn_sched_barrier(0);

  // ---- main loop: pairs (t, t+1), full pipeline while t+3 < TK
  for (int t = 0; t + 3 < TK; t += 2) {
    // even step: compute tile t (buf0); stage tile t+1 (buf1)
    stageA(t + 1, 1);                      // +4 (oldest this step)
    __builtin_amdgcn_sched_barrier(0);
    loadQWf(t + 2, wE0, wE1);              // +2
    loadSZf((t >> 1) + 1, sN, zN);         // +2 (group for tiles t+2,t+3)
    writeB(wO0, wO1, sC, zC, 1);           // tile t+1 (auto-wait leaves 8 newest)
    mfma_tile(0);
    __builtin_amdgcn_sched_barrier(0);
    WAIT_LGKM0;                            // B(t+1) ds_writes visible
    WAIT_VM(4);                            // A(t+1) done; QW(t+2)+SZ stay
    __builtin_amdgcn_s_barrier();
    __builtin_amdgcn_sched_barrier(0);

    // odd step: compute tile t+1 (buf1); stage tile t+2 (buf0)
    stageA(t + 2, 0);                      // +4
    __builtin_amdgcn_sched_barrier(0);
    loadQWf(t + 3, wO0, wO1);              // +2
    writeB(wE0, wE1, sN, zN, 0);           // tile t+2
    mfma_tile(1);
    __builtin_amdgcn_sched_barrier(0);
    WAIT_LGKM0;
    WAIT_VM(2);                            // A(t+2) done; QW(t+3) stays
    __builtin_amdgcn_s_barrier();
    __builtin_amdgcn_sched_barrier(0);

    sC = sN; zC = zN;                      // rotate group scale/zero
  }

  // ---- tail: tiles TK-2 (in buf0) and TK-1
  stageA(TK - 1, 1);
  __builtin_amdgcn_sched_barrier(0);
  writeB(wO0, wO1, sC, zC, 1);             // tile TK-1
  mfma_tile(0);                            // tile TK-2
  __builtin_amdgcn_sched_barrier(0);
  WAIT_LGKM0;
  WAIT_VM(0);                              // tail drain is fine
  __builtin_amdgcn_s_barrier();
  __builtin_amdgcn_sched_barrier(0);
  mfma_tile(1);                            // tile TK-1

  // ---- epilogue: C/D layout col = lane&15, row = (lane>>4)*4 + j
  #pragma unroll
  for (int ni = 0; ni < 4; ++ni) {
    const int gn = n0 + wc * 64 + ni * 16 + (lane & 15);
    const float bv = BS[gn];
    #pragma unroll
    for (int mi = 0; mi < 4; ++mi) {
      const int gm = m0 + wr * 64 + mi * 16 + ((lane >> 4) << 2);
      #pragma unroll
      for (int j = 0; j < 4; ++j)
        OUT[(size_t)(gm + j) * Nd + gn] = acc[mi][ni][j] + bv;
    }
  }
}

// ---------------- fallback (no workspace): round-3 structure, fp32 A inline ----
__global__ __launch_bounds__(THREADS, 2)
void qgemm_fb(const float* __restrict__ X,
              const int* __restrict__ QW, const int* __restrict__ QZ,
              const float* __restrict__ SC, const float* __restrict__ BS,
              float* __restrict__ OUT)
{
  extern __shared__ char smem[];
  unsigned short* As = (unsigned short*)smem;                      // [2][AS_T]
  unsigned short* Bs = (unsigned short*)(smem + 2 * AS_T * 2);     // [BS_T]

  const int nwg = gridDim.x, cpx = nwg >> 3, b = blockIdx.x;
  const int swz = (b & 7) * cpx + (b >> 3);
  const int bm = swz / (Nd / BN), bn = swz % (Nd / BN);
  const int m0 = bm * BM, n0 = bn * BN;
  const int tid = threadIdx.x, lane = tid & 63, wid = tid >> 6;
  const int wr = wid >> 1, wc = wid & 1;
  const int n_l = tid & 127;
  const int k8b = (tid >> 7) * 2;
  const int nab = n0 + n_l;

  f4 acc[4][4];
  #pragma unroll
  for (int i = 0; i < 4; ++i)
    #pragma unroll
    for (int j = 0; j < 4; ++j) acc[i][j] = {0.0f, 0.0f, 0.0f, 0.0f};

  auto stageA_f = [&](int t, int buf) {
    #pragma unroll
    for (int i = 0; i < 4; ++i) {
      const int c = i * THREADS + tid;
      const int r = c >> 3, kbl = c & 7;
      const f4* src = (const f4*)(X + (size_t)(m0 + r) * Kd + t * BK + ((kbl ^ (r & 7)) << 3));
      f4 a = src[0], bb = src[1];
      uint4 o;
      o.x = cvtpk(a[0], a[1]); o.y = cvtpk(a[2], a[3]);
      o.z = cvtpk(bb[0], bb[1]); o.w = cvtpk(bb[2], bb[3]);
      *(uint4*)(As + buf * AS_T + c * 8) = o;
    }
  };
  auto loadB = [&](int t, int* w, float& s, float& negc) {
    const int* qp = QW + (size_t)(t * 8 + k8b) * Nd + nab;
    w[0] = qp[0]; w[1] = qp[Nd];
    const int g = t >> 1;
    s = SC[(size_t)g * Nd + nab];
    const int z32 = QZ[(size_t)g * (Nd / 8) + (nab >> 3)];
    const int z = (z32 >> ((nab & 7) * 4)) & 15;
    negc = -(float)(z + 1) * s;
  };
  auto writeB = [&](const int* w, float s, float negc) {
    #pragma unroll
    for (int i = 0; i < 2; ++i) {
      const unsigned q = (unsigned)w[i];
      const int k8 = k8b + i;
      float f[8];
      #pragma unroll
      for (int j = 0; j < 8; ++j)
        f[j] = __builtin_fmaf((float)((q >> (4 * j)) & 15u), s, negc);
      uint4 o;
      o.x = cvtpk(f[0], f[1]); o.y = cvtpk(f[2], f[3]);
      o.z = cvtpk(f[4], f[5]); o.w = cvtpk(f[6], f[7]);
      *(uint4*)(Bs + n_l * BK + ((k8 ^ (n_l & 7)) << 3)) = o;
    }
  };

  int bw[2]; float sS, sNC; int nbw[2]; float nS, nNC;
  stageA_f(0, 0);
  loadB(0, bw, sS, sNC);
  writeB(bw, sS, sNC);
  __syncthreads();
  for (int t = 0; t < TK; ++t) {
    const int cb = t & 1;
    if (t + 1 < TK) loadB(t + 1, nbw, nS, nNC);
    #pragma unroll
    for (int ks = 0; ks < 2; ++ks) {
      b8 af[4], bf[4];
      const int kb = ks * 4 + (lane >> 4);
      #pragma unroll
      for (int mi = 0; mi < 4; ++mi) {
        const int r = wr * 64 + mi * 16 + (lane & 15);
        af[mi] = *(const b8*)&As[cb * AS_T + r * BK + ((kb ^ (r & 7)) << 3)];
      }
      #pragma unroll
      for (int ni = 0; ni < 4; ++ni) {
        const int cc = wc * 64 + ni * 16 + (lane & 15);
        bf[ni] = *(const b8*)&Bs[cc * BK + ((kb ^ (cc & 7)) << 3)];
      }
      #pragma unroll
      for (int mi = 0; mi < 4; ++mi)
        #pragma unroll
        for (int ni = 0; ni < 4; ++ni)
          acc[mi][ni] = __builtin_amdgcn_mfma_f32_16x16x32_bf16(af[mi], bf[ni], acc[mi][ni], 0, 0, 0);
    }
    __syncthreads();
    if (t + 1 < TK) {
      stageA_f(t + 1, cb ^ 1);
      writeB(nbw, nS, nNC);
    }
    __syncthreads();
  }
  #pragma unroll
  for (int ni = 0; ni < 4; ++ni) {
    const int gn = n0 + wc * 64 + ni * 16 + (lane & 15);
    const float bv = BS[gn];
    #pragma unroll
    for (int mi = 0; mi < 4; ++mi) {
      const int gm = m0 + wr * 64 + mi * 16 + ((lane >> 4) << 2);
      #pragma unroll
      for (int j = 0; j < 4; ++j)
        OUT[(size_t)(gm + j) * Nd + gn] = acc[mi][ni][j] + bv;
    }
  }
}
} // namespace

extern "C" void kernel_launch(void* const* d_in, const int* in_sizes, int n_in,
                              void* d_out, int out_size, void* d_ws, size_t ws_size,
                              hipStream_t stream) {
  const float* x  = (const float*)d_in[0];
  const int*   qw = (const int*)d_in[1];
  const int*   qz = (const int*)d_in[2];
  const float* sc = (const float*)d_in[3];
  const float* bs = (const float*)d_in[4];
  float* out = (float*)d_out;

  (void)hipFuncSetAttribute((const void*)qgemm4,
                            hipFuncAttributeMaxDynamicSharedMemorySize, LDS_BYTES);
  (void)hipFuncSetAttribute((const void*)qgemm_fb,
                            hipFuncAttributeMaxDynamicSharedMemorySize, LDS_FB);

  dim3 grid((Md / BM) * (Nd / BN));   // 16 * 96 = 1536
  if (ws_size >= A_BYTES) {
    unsigned short* xb = (unsigned short*)d_ws;
    const int n8 = Md * Kd / 8;
    cvtA_kernel<<<2048, 256, 0, stream>>>(x, xb, n8);
    qgemm4<<<grid, dim3(THREADS), LDS_BYTES, stream>>>(xb, qw, qz, sc, bs, out);
  } else {
    qgemm_fb<<<grid, dim3(THREADS), LDS_FB, stream>>>(x, qw, qz, sc, bs, out);
  }
}

// Round 6
// 419.307 us; speedup vs baseline: 1.4065x; 1.2026x over previous
//
#include <hip/hip_runtime.h>
#include <hip/hip_bf16.h>

namespace {
constexpr int Md = 4096, Kd = 4096, Nd = 12288;
constexpr int BM = 256, BN = 128, BK = 64;
constexpr int TK = Kd / BK;                        // 64
constexpr int THREADS = 512;
constexpr size_t A_BYTES = (size_t)Md * Kd * 2;    // fp16 copy of X in d_ws
constexpr int AS_T = BM * BK;                      // shorts per A tile (16384)
constexpr int BS_T = BN * BK;                      // shorts per B tile (8192)
constexpr int LDS_BYTES = (2 * AS_T + BS_T) * 2;   // 81920 -> 2 blocks/CU

typedef __attribute__((ext_vector_type(4))) float f4;
typedef __attribute__((ext_vector_type(8))) _Float16 h8;
typedef __attribute__((ext_vector_type(2))) _Float16 h2;

constexpr unsigned M4  = 0x000F000Fu;
constexpr unsigned MAG = 0x64006400u;              // fp16 1024.0 in both halves

__device__ __forceinline__ unsigned pkrtz(float lo, float hi) {
  return __builtin_bit_cast(unsigned, __builtin_amdgcn_cvt_pkrtz(lo, hi));
}

// A pre-pass: fp32 -> fp16 with per-8-chunk k-permutation [0,4,1,5,2,6,3,7]
// (matches the order B's magic-dequant emits; MFMA sums over k, so any
//  permutation applied identically to A and B is exact.)
__global__ __launch_bounds__(256)
void cvtA_kernel(const float* __restrict__ X, unsigned short* __restrict__ Xb, int n8) {
  int i = blockIdx.x * blockDim.x + threadIdx.x;
  const int stride = gridDim.x * blockDim.x;
  for (; i < n8; i += stride) {
    const f4* p = (const f4*)X + (size_t)i * 2;
    f4 a = p[0], b = p[1];                         // x0..x3, x4..x7
    uint4 o;
    o.x = pkrtz(a[0], b[0]);                       // (x0, x4)
    o.y = pkrtz(a[1], b[1]);                       // (x1, x5)
    o.z = pkrtz(a[2], b[2]);                       // (x2, x6)
    o.w = pkrtz(a[3], b[3]);                       // (x3, x7)
    ((uint4*)Xb)[i] = o;
  }
}

template<bool AWS>
__global__ __launch_bounds__(THREADS, 4)
void qgemm5(const float* __restrict__ X, const unsigned short* __restrict__ Xb,
            const int* __restrict__ QW, const int* __restrict__ QZ,
            const float* __restrict__ SC, const float* __restrict__ BS,
            float* __restrict__ OUT)
{
  extern __shared__ char smem[];
  unsigned short* As = (unsigned short*)smem;                      // [2][AS_T]
  unsigned short* Bs = (unsigned short*)(smem + 2 * AS_T * 2);     // [BS_T]

  const int nwg = gridDim.x, cpx = nwg >> 3, b = blockIdx.x;
  const int swz = (b & 7) * cpx + (b >> 3);       // 1536 % 8 == 0 -> bijective
  const int bm = swz / (Nd / BN), bn = swz % (Nd / BN);
  const int m0 = bm * BM, n0 = bn * BN;

  const int tid = threadIdx.x, lane = tid & 63, wid = tid >> 6;
  const int wr = wid >> 1, wc = wid & 1;          // 4x2 waves, each 64x64
  const int n_l = tid & 127;
  const int k8b = (tid >> 7) * 2;                 // first of 2 k8-rows
  const int nab = n0 + n_l;

  f4 acc[4][4];
  #pragma unroll
  for (int i = 0; i < 4; ++i)
    #pragma unroll
    for (int j = 0; j < 4; ++j) acc[i][j] = {0.0f, 0.0f, 0.0f, 0.0f};

  // --- A staging: linear LDS dest, pre-swizzled global source (kb ^ (r&7)) ---
  auto stageA = [&](int t, int buf) {
    #pragma unroll
    for (int i = 0; i < 4; ++i) {
      const int c = i * THREADS + tid;            // 16B chunk index
      const int r = c >> 3, kbl = c & 7;
      const unsigned short* src = Xb + (size_t)(m0 + r) * Kd + t * BK + ((kbl ^ (r & 7)) << 3);
      __builtin_amdgcn_global_load_lds(
          (const __attribute__((address_space(1))) unsigned*)src,
          (__attribute__((address_space(3))) unsigned*)(As + buf * AS_T + c * 8),
          16, 0, 0);
    }
  };
  auto stageA_f = [&](int t, int buf) {           // fallback: fp32 + pkrtz permute
    #pragma unroll
    for (int i = 0; i < 4; ++i) {
      const int c = i * THREADS + tid;
      const int r = c >> 3, kbl = c & 7;
      const f4* src = (const f4*)(X + (size_t)(m0 + r) * Kd + t * BK + ((kbl ^ (r & 7)) << 3));
      f4 a = src[0], bb = src[1];
      uint4 o;
      o.x = pkrtz(a[0], bb[0]); o.y = pkrtz(a[1], bb[1]);
      o.z = pkrtz(a[2], bb[2]); o.w = pkrtz(a[3], bb[3]);
      *(uint4*)(As + buf * AS_T + c * 8) = o;
    }
  };

  // --- B: packed words + scale/zero -> fp16x2 constants ---
  auto loadB = [&](int t, int* w, unsigned& hs2, unsigned& hz2) {
    const int* qp = QW + (size_t)(t * 8 + k8b) * Nd + nab;
    w[0] = qp[0];
    w[1] = qp[Nd];
    const int g = t >> 1;                         // BK=64: group constant per tile
    const float s = SC[(size_t)g * Nd + nab];
    const int z32 = QZ[(size_t)g * (Nd / 8) + (nab >> 3)];
    const int z = (z32 >> ((nab & 7) * 4)) & 15;
    const unsigned hz = 0x6400u + (unsigned)z + 1u;   // fp16(1025+z), exact
    hz2 = hz * 0x10001u;
    const unsigned short hs = __builtin_bit_cast(unsigned short, (_Float16)s);
    hs2 = (unsigned)hs * 0x10001u;
  };
  auto writeB = [&](const int* w, unsigned hs2, unsigned hz2) {
    const h2 vz = __builtin_bit_cast(h2, hz2);
    const h2 vs = __builtin_bit_cast(h2, hs2);
    #pragma unroll
    for (int i = 0; i < 2; ++i) {
      const unsigned q = (unsigned)w[i];
      const int k8 = k8b + i;
      // magic unpack: (1024+n) pairs, k-order [0,4][1,5][2,6][3,7]
      const unsigned p0 = (q & M4) | MAG;
      const unsigned p1 = ((q >> 4) & M4) | MAG;
      const unsigned p2 = ((q >> 8) & M4) | MAG;
      const unsigned p3 = ((q >> 12) & M4) | MAG;
      // (1024+n) - (1025+z) exact, then * s: one rounding (2^-11 rel)
      const h2 f0 = (__builtin_bit_cast(h2, p0) - vz) * vs;
      const h2 f1 = (__builtin_bit_cast(h2, p1) - vz) * vs;
      const h2 f2 = (__builtin_bit_cast(h2, p2) - vz) * vs;
      const h2 f3 = (__builtin_bit_cast(h2, p3) - vz) * vs;
      uint4 o;
      o.x = __builtin_bit_cast(unsigned, f0);
      o.y = __builtin_bit_cast(unsigned, f1);
      o.z = __builtin_bit_cast(unsigned, f2);
      o.w = __builtin_bit_cast(unsigned, f3);
      *(uint4*)(Bs + n_l * BK + ((k8 ^ (n_l & 7)) << 3)) = o;
    }
  };

  auto mfma_tile = [&](int cb) {
    const unsigned short* Ab = As + cb * AS_T;
    #pragma unroll
    for (int ks = 0; ks < 2; ++ks) {
      h8 af[4], bf[4];
      const int kb = ks * 4 + (lane >> 4);
      #pragma unroll
      for (int mi = 0; mi < 4; ++mi) {
        const int r = wr * 64 + mi * 16 + (lane & 15);
        af[mi] = *(const h8*)&Ab[r * BK + ((kb ^ (r & 7)) << 3)];
      }
      #pragma unroll
      for (int ni = 0; ni < 4; ++ni) {
        const int cc = wc * 64 + ni * 16 + (lane & 15);
        bf[ni] = *(const h8*)&Bs[cc * BK + ((kb ^ (cc & 7)) << 3)];
      }
      #pragma unroll
      for (int mi = 0; mi < 4; ++mi)
        #pragma unroll
        for (int ni = 0; ni < 4; ++ni)
          acc[mi][ni] = __builtin_amdgcn_mfma_f32_16x16x32_f16(af[mi], bf[ni], acc[mi][ni], 0, 0, 0);
    }
  };

  int bw[2]; unsigned sHS, sHZ;
  int nbw[2]; unsigned nHS, nHZ;

  // prologue: tile 0
  if constexpr (AWS) stageA(0, 0); else stageA_f(0, 0);
  loadB(0, bw, sHS, sHZ);
  writeB(bw, sHS, sHZ);
  __syncthreads();                                 // A0 + B0 visible

  for (int t = 0; t < TK; ++t) {
    const int cb = t & 1;
    if (t + 1 < TK) {
      if constexpr (AWS) stageA(t + 1, cb ^ 1);    // DMA in flight across MFMA
      loadB(t + 1, nbw, nHS, nHZ);
    }
    mfma_tile(cb);
    __syncthreads();                               // Bs reads done (other block covers drain)
    if (t + 1 < TK) {
      if constexpr (!AWS) stageA_f(t + 1, cb ^ 1);
      writeB(nbw, nHS, nHZ);                       // dequant tile t+1 into Bs
    }
    __syncthreads();                               // Bs + A writes visible
  }

  // epilogue: C/D layout col = lane&15, row = (lane>>4)*4 + j
  #pragma unroll
  for (int ni = 0; ni < 4; ++ni) {
    const int gn = n0 + wc * 64 + ni * 16 + (lane & 15);
    const float bv = BS[gn];
    #pragma unroll
    for (int mi = 0; mi < 4; ++mi) {
      const int gm = m0 + wr * 64 + mi * 16 + ((lane >> 4) << 2);
      #pragma unroll
      for (int j = 0; j < 4; ++j)
        OUT[(size_t)(gm + j) * Nd + gn] = acc[mi][ni][j] + bv;
    }
  }
}
} // namespace

extern "C" void kernel_launch(void* const* d_in, const int* in_sizes, int n_in,
                              void* d_out, int out_size, void* d_ws, size_t ws_size,
                              hipStream_t stream) {
  const float* x  = (const float*)d_in[0];
  const int*   qw = (const int*)d_in[1];
  const int*   qz = (const int*)d_in[2];
  const float* sc = (const float*)d_in[3];
  const float* bs = (const float*)d_in[4];
  float* out = (float*)d_out;

  (void)hipFuncSetAttribute((const void*)qgemm5<true>,
                            hipFuncAttributeMaxDynamicSharedMemorySize, LDS_BYTES);
  (void)hipFuncSetAttribute((const void*)qgemm5<false>,
                            hipFuncAttributeMaxDynamicSharedMemorySize, LDS_BYTES);

  dim3 grid((Md / BM) * (Nd / BN));   // 16 * 96 = 1536
  if (ws_size >= A_BYTES) {
    unsigned short* xb = (unsigned short*)d_ws;
    const int n8 = Md * Kd / 8;
    cvtA_kernel<<<2048, 256, 0, stream>>>(x, xb, n8);
    qgemm5<true><<<grid, dim3(THREADS), LDS_BYTES, stream>>>(x, xb, qw, qz, sc, bs, out);
  } else {
    qgemm5<false><<<grid, dim3(THREADS), LDS_BYTES, stream>>>(x, nullptr, qw, qz, sc, bs, out);
  }
}